// Round 1
// baseline (69.801 us; speedup 1.0000x reference)
//
#include <hip/hip_runtime.h>

// SeparateLoss reduces algebraically:
//   mean(mask * simi) = 2 * dot(S0, S1) / N^2
// where S0/S1 = sums of L2-normalized feature rows with label 0/1.
// N = 4*64*64 = 16384 rows, C = 64 channels, nearest-resize = stride-2 pick.

#define H 128
#define W 128
#define C 64
#define OSIZE 64
#define NROWS (4 * OSIZE * OSIZE) // 16384
#define NBLK 256                  // 4 batches * 64 output rows

// Phase 1: one block per (b, i_out). Produces per-block partial sums
// partials[blk][0:64] = S0 contribution, partials[blk][64:128] = S1.
__global__ __launch_bounds__(256) void separate_loss_phase1(
    const float* __restrict__ feat,   // [4][64][128][128]
    const int*   __restrict__ label,  // [4][1][128][128]
    float*       __restrict__ partials /* [NBLK][128] */) {

    __shared__ float tile[C][OSIZE + 1]; // +1 pad: 2-way bank conflicts max (free)
    __shared__ float linv[OSIZE];
    __shared__ int   lab[OSIZE];
    __shared__ float p0[4][C];
    __shared__ float p1[4][C];

    const int blk = blockIdx.x;   // 0..255
    const int b   = blk >> 6;     // batch 0..3
    const int i   = blk & 63;     // output row -> input row 2*i
    const int t   = threadIdx.x;
    const int j   = t & 63;       // output col lane
    const int q   = t >> 6;       // quarter 0..3 (wave id)

    // --- Stage feat[b][c][2i][2j] for all (c, j) into LDS.
    // float2 load at even positions; keep .x. Each wave: 64 consecutive
    // float2 = 512B contiguous -> coalesced.
    const float2* fbase = (const float2*)(feat + ((b * C) * H + 2 * i) * W);
    #pragma unroll
    for (int c0 = 0; c0 < C; c0 += 4) {
        const int c = c0 + q;
        float2 v = fbase[c * (H * W / 2) + j];
        tile[c][j] = v.x;
    }
    __syncthreads();

    // --- Per-row (j) norm: lanes j read tile[c][j], consecutive addresses
    // per iteration -> conflict-free.
    if (t < 64) {
        float ss = 0.0f;
        #pragma unroll
        for (int c = 0; c < C; ++c) {
            const float v = tile[c][t];
            ss += v * v;
        }
        const float nrm = sqrtf(ss);
        linv[t] = 1.0f / fmaxf(nrm, 1e-12f); // torch F.normalize eps semantics
        lab[t]  = label[(b * H + 2 * i) * W + 2 * t];
    }
    __syncthreads();

    // --- Accumulate normalized values into label-split per-channel sums.
    // Wave q handles j in [16q, 16q+16); lane = channel c. tile[c][jj]
    // across lanes: banks (c+jj)%32 -> 2-way (free).
    {
        const int c = t & 63;
        float s0 = 0.0f, s1 = 0.0f;
        #pragma unroll
        for (int k = 0; k < 16; ++k) {
            const int jj = q * 16 + k;
            const float v = tile[c][jj] * linv[jj];
            if (lab[jj] == 0) s0 += v; else s1 += v;
        }
        p0[q][c] = s0;
        p1[q][c] = s1;
    }
    __syncthreads();

    if (t < 64) {
        const float a0 = p0[0][t] + p0[1][t] + p0[2][t] + p0[3][t];
        const float a1 = p1[0][t] + p1[1][t] + p1[2][t] + p1[3][t];
        partials[blk * 128 + t]      = a0;
        partials[blk * 128 + 64 + t] = a1;
    }
}

// Phase 2: reduce partials -> S0, S1 (64 floats each), out = 2*S0.S1/N^2.
__global__ __launch_bounds__(128) void separate_loss_phase2(
    const float* __restrict__ partials, float* __restrict__ out) {
    __shared__ float S[128];
    const int t = threadIdx.x;
    float s = 0.0f;
    for (int blk = 0; blk < NBLK; ++blk)
        s += partials[blk * 128 + t]; // coalesced across t
    S[t] = s;
    __syncthreads();
    if (t < 64) {
        float p = S[t] * S[64 + t];
        #pragma unroll
        for (int off = 32; off > 0; off >>= 1)
            p += __shfl_down(p, off, 64);
        if (t == 0)
            out[0] = 2.0f * p / ((float)NROWS * (float)NROWS);
    }
}

extern "C" void kernel_launch(void* const* d_in, const int* in_sizes, int n_in,
                              void* d_out, int out_size, void* d_ws, size_t ws_size,
                              hipStream_t stream) {
    const float* feat  = (const float*)d_in[0];
    const int*   label = (const int*)d_in[1];
    float* out      = (float*)d_out;
    float* partials = (float*)d_ws; // needs NBLK*128*4 = 128 KiB, fully
                                    // overwritten by phase1 every call
    separate_loss_phase1<<<NBLK, 256, 0, stream>>>(feat, label, partials);
    separate_loss_phase2<<<1, 128, 0, stream>>>(partials, out);
}